// Round 6
// baseline (146.691 us; speedup 1.0000x reference)
//
// Performer FAVOR+ on MI355X — R6: R4's proven LDS layout; GEMM2 (P@V) in
// single bf16 (1 MFMA, was 3) with identical addressing. p2 unchanged.
#include <hip/hip_runtime.h>

typedef short short8 __attribute__((ext_vector_type(8)));
typedef float f32x4 __attribute__((ext_vector_type(4)));

namespace {
constexpr int Sc = 8192, Dc = 64;
constexpr int NH = 64;                 // B*H heads
constexpr int CH = 1024;               // rows per block
constexpr int TPT = CH / 64;           // 16 tiles of 64 rows
constexpr int NCHUNK = Sc / CH;        // 8
constexpr size_t DEN_OFF = (size_t)NH * 4096;            // floats
constexpr size_t WT_OFF_BYTES = (DEN_OFF + NH * 64) * 4; // bytes
}

__device__ __forceinline__ unsigned bf16rtne(float x) {
  unsigned u = __builtin_bit_cast(unsigned, x);
  return (u + 0x7fffu + ((u >> 16) & 1u)) >> 16;
}
// pack f32 -> (bf16_hi RTNE) | (bf16_lo residual) << 16
__device__ __forceinline__ unsigned pkhl(float x) {
  unsigned u = __builtin_bit_cast(unsigned, x);
  unsigned rh = (u + 0x7fffu + ((u >> 16) & 1u)) & 0xffff0000u;
  float res = x - __builtin_bit_cast(float, rh);
  return (rh >> 16) | (__builtin_bit_cast(unsigned, res) & 0xffff0000u);
}
__device__ __forceinline__ void bsplit(float x, short& hi, short& lo) {
  unsigned p = pkhl(x);
  hi = (short)(p & 0xffff);
  lo = (short)(p >> 16);
}
// extract 8 hi-bf16 (low16 of each u32) / 8 lo-bf16 (high16) via v_perm
__device__ __forceinline__ short8 exhi(uint4 q0, uint4 q1) {
  union { unsigned u[4]; short8 s; } r;
  r.u[0] = __builtin_amdgcn_perm(q0.y, q0.x, 0x05040100u);
  r.u[1] = __builtin_amdgcn_perm(q0.w, q0.z, 0x05040100u);
  r.u[2] = __builtin_amdgcn_perm(q1.y, q1.x, 0x05040100u);
  r.u[3] = __builtin_amdgcn_perm(q1.w, q1.z, 0x05040100u);
  return r.s;
}
__device__ __forceinline__ short8 exlo(uint4 q0, uint4 q1) {
  union { unsigned u[4]; short8 s; } r;
  r.u[0] = __builtin_amdgcn_perm(q0.y, q0.x, 0x07060302u);
  r.u[1] = __builtin_amdgcn_perm(q0.w, q0.z, 0x07060302u);
  r.u[2] = __builtin_amdgcn_perm(q1.y, q1.x, 0x07060302u);
  r.u[3] = __builtin_amdgcn_perm(q1.w, q1.z, 0x07060302u);
  return r.s;
}

__global__ void p0(const float* __restrict__ omega, short* __restrict__ wT) {
  int i = blockIdx.x * 256 + threadIdx.x;
  if (i < 4096) {
    int m = i >> 6, d = i & 63;
    short hi, lo;
    bsplit(omega[d * 64 + m], hi, lo);
    wT[m * 64 + d] = hi;
    wT[4096 + m * 64 + d] = lo;
  }
}

// ---------------- Phase 1: B1[m][c] = sum_s k'[s][m] V[s][c]; den[m] = sum_s k'[s][m]
__global__ __launch_bounds__(256, 2) void p1(
    const float* __restrict__ Kg, const float* __restrict__ Vg,
    const short* __restrict__ wT, float* __restrict__ b1, float* __restrict__ den) {
  __shared__ unsigned Kpk[64 * 68];  // K tile packed hi|lo, [row][d] stride 68
  __shared__ unsigned VT[64 * 68];   // V^T bf16 in low16, [c][s ^ 4*((c>>3)&7)]
  __shared__ unsigned PT[64 * 68];   // k'^T bf16 in low16, [m][s] stride 68
  __shared__ float ssq[64];

  const int t = threadIdx.x;
  const int lane = t & 63;
  const int w = t >> 6;      // wave 0..3
  const int a = lane & 15;
  const int g = lane >> 4;   // 0..3
  const int bh = blockIdx.x / NCHUNK, ch = blockIdx.x % NCHUNK;
  const float* Kb = Kg + ((size_t)bh * Sc + (size_t)ch * CH) * Dc;
  const float* Vb = Vg + ((size_t)bh * Sc + (size_t)ch * CH) * Dc;

  // omega B-frags: lane holds w[d=32ks+8g+j][m=16mt+a]
  short8 wfh[4][2], wfl[4][2];
#pragma unroll
  for (int mt = 0; mt < 4; ++mt)
#pragma unroll
    for (int ks = 0; ks < 2; ++ks) {
      int off = (a + 16 * mt) * 64 + 32 * ks + 8 * g;
      wfh[mt][ks] = *(const short8*)(wT + off);
      wfl[mt][ks] = *(const short8*)(wT + 4096 + off);
    }

  float4 kreg[4], vreg[4];
  auto load_tile = [&](int tile) {
    const float4* Kt = (const float4*)(Kb + (size_t)tile * 64 * Dc);
    const float4* Vt = (const float4*)(Vb + (size_t)tile * 64 * Dc);
#pragma unroll
    for (int rr = 0; rr < 4; ++rr) {
      kreg[rr] = Kt[rr * 256 + t];
      vreg[rr] = Vt[rr * 256 + t];
    }
  };
  auto store_tile = [&]() {
#pragma unroll
    for (int rr = 0; rr < 4; ++rr) {
      int idx = rr * 256 + t;
      int row = idx >> 4;   // 0..63
      int c4 = idx & 15;
      float4 kv = kreg[rr];
      uint4 kp;
      kp.x = pkhl(kv.x); kp.y = pkhl(kv.y);
      kp.z = pkhl(kv.z); kp.w = pkhl(kv.w);
      *(uint4*)&Kpk[row * 68 + 4 * c4] = kp;  // uniform-8 banks
      float ps = kv.x * kv.x + kv.y * kv.y + kv.z * kv.z + kv.w * kv.w;
      ps += __shfl_xor(ps, 1, 64); ps += __shfl_xor(ps, 2, 64);
      ps += __shfl_xor(ps, 4, 64); ps += __shfl_xor(ps, 8, 64);
      if (c4 == 0) ssq[row] = ps;
      // V transpose, XOR-swizzled s (2-way writes); single bf16 in low16
      float4 vv = vreg[rr];
      int sw = row ^ (4 * ((c4 >> 1) & 7));
      VT[(4 * c4 + 0) * 68 + sw] = bf16rtne(vv.x);
      VT[(4 * c4 + 1) * 68 + sw] = bf16rtne(vv.y);
      VT[(4 * c4 + 2) * 68 + sw] = bf16rtne(vv.z);
      VT[(4 * c4 + 3) * 68 + sw] = bf16rtne(vv.w);
    }
  };

  f32x4 B1a[4];
#pragma unroll
  for (int ct = 0; ct < 4; ++ct) B1a[ct] = (f32x4){0.f, 0.f, 0.f, 0.f};
  float dpart[4] = {0.f, 0.f, 0.f, 0.f};

  load_tile(0);
  store_tile();
  __syncthreads();

  for (int tile = 0; tile < TPT; ++tile) {
    if (tile + 1 < TPT) load_tile(tile + 1);

    // GEMM1: X[s][m] = K @ omega (3-product split; feeds exp -> keep precise)
    f32x4 X[4];
#pragma unroll
    for (int mt = 0; mt < 4; ++mt) X[mt] = (f32x4){0.f, 0.f, 0.f, 0.f};
#pragma unroll
    for (int ks = 0; ks < 2; ++ks) {
      const unsigned* kb = &Kpk[(16 * w + a) * 68 + 32 * ks + 8 * g];
      uint4 q0 = *(const uint4*)kb;
      uint4 q1 = *(const uint4*)(kb + 4);
      short8 ah = exhi(q0, q1), al = exlo(q0, q1);
#pragma unroll
      for (int mt = 0; mt < 4; ++mt) {
        X[mt] = __builtin_amdgcn_mfma_f32_16x16x32_bf16(ah, wfh[mt][ks], X[mt], 0, 0, 0);
        X[mt] = __builtin_amdgcn_mfma_f32_16x16x32_bf16(ah, wfl[mt][ks], X[mt], 0, 0, 0);
        X[mt] = __builtin_amdgcn_mfma_f32_16x16x32_bf16(al, wfh[mt][ks], X[mt], 0, 0, 0);
      }
    }

    // exp -> k'; f32 for den, single bf16 (low16) for the P@V product
    float sq[4];
#pragma unroll
    for (int r = 0; r < 4; ++r) sq[r] = ssq[16 * w + 4 * g + r];
#pragma unroll
    for (int mt = 0; mt < 4; ++mt) {
      uint4 pp;
      float p_;
      p_ = 0.125f * __expf(X[mt][0] - 0.5f * sq[0]); dpart[mt] += p_; pp.x = bf16rtne(p_);
      p_ = 0.125f * __expf(X[mt][1] - 0.5f * sq[1]); dpart[mt] += p_; pp.y = bf16rtne(p_);
      p_ = 0.125f * __expf(X[mt][2] - 0.5f * sq[2]); dpart[mt] += p_; pp.z = bf16rtne(p_);
      p_ = 0.125f * __expf(X[mt][3] - 0.5f * sq[3]); dpart[mt] += p_; pp.w = bf16rtne(p_);
      *(uint4*)&PT[(16 * mt + a) * 68 + 16 * w + 4 * g] = pp;  // uniform-8
    }
    __syncthreads();  // A: PT visible, Kpk reads done

    // GEMM2: B1 += P^T @ V  (single bf16, 1 MFMA per fragment)
#pragma unroll
    for (int ks = 0; ks < 2; ++ks) {
      const unsigned* pb = &PT[(16 * w + a) * 68 + 32 * ks + 8 * g];
      uint4 r0 = *(const uint4*)pb;
      uint4 r1 = *(const uint4*)(pb + 4);
      short8 pah = exhi(r0, r1);
#pragma unroll
      for (int ct = 0; ct < 4; ++ct) {
        int c = 16 * ct + a;
        int kk4 = 4 * ((2 * ct + (a >> 3)) & 7);
        int s0 = (32 * ks + 8 * g) ^ kk4;
        int s1 = (32 * ks + 8 * g + 4) ^ kk4;
        const unsigned* vb = &VT[c * 68];
        uint4 v0 = *(const uint4*)(vb + s0);
        uint4 v1 = *(const uint4*)(vb + s1);
        short8 vh = exhi(v0, v1);
        B1a[ct] = __builtin_amdgcn_mfma_f32_16x16x32_bf16(pah, vh, B1a[ct], 0, 0, 0);
      }
    }
    __syncthreads();  // B: VT/PT reads done
    if (tile + 1 < TPT) store_tile();
    __syncthreads();  // C: staged data visible
  }

  float* b1h = b1 + (size_t)bh * 4096;
#pragma unroll
  for (int ct = 0; ct < 4; ++ct)
#pragma unroll
    for (int r = 0; r < 4; ++r)
      atomicAdd(&b1h[(16 * w + 4 * g + r) * 64 + 16 * ct + a], B1a[ct][r]);
#pragma unroll
  for (int mt = 0; mt < 4; ++mt) {
    float v = dpart[mt];
    v += __shfl_xor(v, 16, 64);
    v += __shfl_xor(v, 32, 64);
    if (g == 0) atomicAdd(&den[bh * 64 + 16 * mt + a], v);
  }
}

// ---------------- Phase 2 (unchanged from R4 — at HBM roofline)
__global__ __launch_bounds__(256, 2) void p2(
    const float* __restrict__ Qg, const short* __restrict__ wT,
    const float* __restrict__ b1, const float* __restrict__ den,
    float* __restrict__ out) {
  __shared__ unsigned Qpk[64 * 68];
  __shared__ unsigned QP[64 * 68];
  __shared__ short B1h[64 * 72], B1l[64 * 72];
  __shared__ float denv[64];
  __shared__ float ssq[64];

  const int t = threadIdx.x;
  const int lane = t & 63;
  const int w = t >> 6;
  const int a = lane & 15;
  const int g = lane >> 4;
  const int bh = blockIdx.x / NCHUNK, ch = blockIdx.x % NCHUNK;
  const float* Qb = Qg + ((size_t)bh * Sc + (size_t)ch * CH) * Dc;

  short8 wfh[4][2], wfl[4][2];
#pragma unroll
  for (int mt = 0; mt < 4; ++mt)
#pragma unroll
    for (int ks = 0; ks < 2; ++ks) {
      int off = (a + 16 * mt) * 64 + 32 * ks + 8 * g;
      wfh[mt][ks] = *(const short8*)(wT + off);
      wfl[mt][ks] = *(const short8*)(wT + 4096 + off);
    }

  const float* b1g = b1 + (size_t)bh * 4096;
  for (int i = t; i < 4096; i += 256) {
    int m = i >> 6, c = i & 63;
    short hi, lo;
    bsplit(b1g[i], hi, lo);
    B1h[c * 72 + m] = hi;
    B1l[c * 72 + m] = lo;
  }
  if (t < 64) denv[t] = den[bh * 64 + t];

  float4 qreg[4];
  auto load_tile = [&](int tile) {
    const float4* Qt = (const float4*)(Qb + (size_t)tile * 64 * Dc);
#pragma unroll
    for (int rr = 0; rr < 4; ++rr) qreg[rr] = Qt[rr * 256 + t];
  };
  auto store_tile = [&]() {
#pragma unroll
    for (int rr = 0; rr < 4; ++rr) {
      int idx = rr * 256 + t;
      int row = idx >> 4;
      int c4 = idx & 15;
      float4 kv = qreg[rr];
      uint4 qp;
      qp.x = pkhl(kv.x); qp.y = pkhl(kv.y);
      qp.z = pkhl(kv.z); qp.w = pkhl(kv.w);
      *(uint4*)&Qpk[row * 68 + 4 * c4] = qp;
      float ps = kv.x * kv.x + kv.y * kv.y + kv.z * kv.z + kv.w * kv.w;
      ps += __shfl_xor(ps, 1, 64); ps += __shfl_xor(ps, 2, 64);
      ps += __shfl_xor(ps, 4, 64); ps += __shfl_xor(ps, 8, 64);
      if (c4 == 0) ssq[row] = ps;
    }
  };

  load_tile(0);
  store_tile();
  __syncthreads();

  for (int tile = 0; tile < TPT; ++tile) {
    if (tile + 1 < TPT) load_tile(tile + 1);

    f32x4 X[4];
#pragma unroll
    for (int mt = 0; mt < 4; ++mt) X[mt] = (f32x4){0.f, 0.f, 0.f, 0.f};
#pragma unroll
    for (int ks = 0; ks < 2; ++ks) {
      const unsigned* qb = &Qpk[(16 * w + a) * 68 + 32 * ks + 8 * g];
      uint4 q0 = *(const uint4*)qb;
      uint4 q1 = *(const uint4*)(qb + 4);
      short8 ah = exhi(q0, q1), al = exlo(q0, q1);
#pragma unroll
      for (int mt = 0; mt < 4; ++mt) {
        X[mt] = __builtin_amdgcn_mfma_f32_16x16x32_bf16(ah, wfh[mt][ks], X[mt], 0, 0, 0);
        X[mt] = __builtin_amdgcn_mfma_f32_16x16x32_bf16(ah, wfl[mt][ks], X[mt], 0, 0, 0);
        X[mt] = __builtin_amdgcn_mfma_f32_16x16x32_bf16(al, wfh[mt][ks], X[mt], 0, 0, 0);
      }
    }

    float sq[4];
#pragma unroll
    for (int r = 0; r < 4; ++r) sq[r] = ssq[16 * w + 4 * g + r];
    float dv[4];
#pragma unroll
    for (int mt = 0; mt < 4; ++mt) dv[mt] = denv[16 * mt + a];
    float dn[4] = {0.f, 0.f, 0.f, 0.f};
#pragma unroll
    for (int mt = 0; mt < 4; ++mt) {
#pragma unroll
      for (int r = 0; r < 4; ++r) {
        float p_ = 0.125f * __expf(X[mt][r] - 0.5f * sq[r]);
        dn[r] = fmaf(p_, dv[mt], dn[r]);
        QP[(16 * w + 4 * g + r) * 68 + 16 * mt + a] = pkhl(p_);
      }
    }
#pragma unroll
    for (int r = 0; r < 4; ++r) {
      dn[r] += __shfl_xor(dn[r], 1, 64);
      dn[r] += __shfl_xor(dn[r], 2, 64);
      dn[r] += __shfl_xor(dn[r], 4, 64);
      dn[r] += __shfl_xor(dn[r], 8, 64);
    }
    __syncthreads();  // A

    f32x4 O[4];
#pragma unroll
    for (int ct = 0; ct < 4; ++ct) O[ct] = (f32x4){0.f, 0.f, 0.f, 0.f};
#pragma unroll
    for (int ks = 0; ks < 2; ++ks) {
      const unsigned* qb = &QP[(16 * w + a) * 68 + 32 * ks + 8 * g];
      uint4 r0 = *(const uint4*)qb;
      uint4 r1 = *(const uint4*)(qb + 4);
      short8 qh = exhi(r0, r1), ql = exlo(r0, r1);
#pragma unroll
      for (int ct = 0; ct < 4; ++ct) {
        short8 bh_ = *(const short8*)&B1h[(16 * ct + a) * 72 + 32 * ks + 8 * g];
        short8 bl_ = *(const short8*)&B1l[(16 * ct + a) * 72 + 32 * ks + 8 * g];
        O[ct] = __builtin_amdgcn_mfma_f32_16x16x32_bf16(qh, bh_, O[ct], 0, 0, 0);
        O[ct] = __builtin_amdgcn_mfma_f32_16x16x32_bf16(qh, bl_, O[ct], 0, 0, 0);
        O[ct] = __builtin_amdgcn_mfma_f32_16x16x32_bf16(ql, bh_, O[ct], 0, 0, 0);
      }
    }

    float inv[4];
#pragma unroll
    for (int r = 0; r < 4; ++r) inv[r] = 1.0f / dn[r];
    float* ob = out + ((size_t)bh * Sc + (size_t)ch * CH + tile * 64 + 16 * w + 4 * g) * 64;
#pragma unroll
    for (int ct = 0; ct < 4; ++ct)
#pragma unroll
      for (int r = 0; r < 4; ++r)
        ob[r * 64 + 16 * ct + a] = O[ct][r] * inv[r];
    __syncthreads();  // B
    if (tile + 1 < TPT) store_tile();
    __syncthreads();  // C
  }
}

extern "C" void kernel_launch(void* const* d_in, const int* in_sizes, int n_in,
                              void* d_out, int out_size, void* d_ws, size_t ws_size,
                              hipStream_t stream) {
  const float* Q = (const float*)d_in[0];
  const float* K = (const float*)d_in[1];
  const float* V = (const float*)d_in[2];
  const float* omega = (const float*)d_in[3];
  float* outp = (float*)d_out;
  float* b1 = (float*)d_ws;
  float* den = b1 + DEN_OFF;
  short* wT = (short*)((char*)d_ws + WT_OFF_BYTES);

  hipMemsetAsync(d_ws, 0, WT_OFF_BYTES, stream);  // zero b1 + den
  p0<<<16, 256, 0, stream>>>(omega, wT);
  p1<<<NH * NCHUNK, 256, 0, stream>>>(K, V, wT, b1, den);
  p2<<<NH * NCHUNK, 256, 0, stream>>>(Q, wT, b1, den, outp);
}